// Round 1
// baseline (330.860 us; speedup 1.0000x reference)
//
#include <hip/hip_runtime.h>
#include <math.h>

#define N_EDGES    1048576
#define N_CENTERS  32768
#define N_SEG      131072            // N_CENTERS * 4 species
#define N_BASIS    12

// ---- workspace layout ----
#define WS_CURSORS  0                        // int[N_SEG]           (512 KB)
#define WS_OVFCNT   (N_SEG * 4)              // int (+ pad to 64 B)
#define OVF_CAP     65536
#define WS_OVF      (N_SEG * 4 + 64)         // uint2[OVF_CAP]       (512 KB)
#define WS_EIDS     (N_SEG * 4 + 64 + OVF_CAP * 8)   // u32[N_SEG * CAP]

__device__ __forceinline__ void compute_edge(float x, float y, float z,
                                             float* __restrict__ ph,   // 12, scaled by NORM/r
                                             float* __restrict__ sh)   // 16
{
    const float r2    = fmaf(x, x, fmaf(y, y, z * z)) + 1e-12f;
    const float inv_r = rsqrtf(r2);
    const float r     = r2 * inv_r;
    x *= inv_r; y *= inv_r; z *= inv_r;

    const float t = 0.6283185307179586f * r;   // pi/5 * r
    float s1, c1;
    __sincosf(t, &s1, &c1);
    const float twoc = 2.0f * c1;
    const float scale = 0.17677669529663687f * inv_r;  // (1/sqrt(32)) / r
    float skm1 = 0.0f, sk = s1;
    #pragma unroll
    for (int b = 0; b < N_BASIS; ++b) {
        ph[b] = sk * scale;
        const float nxt = fmaf(twoc, sk, -skm1);
        skm1 = sk; sk = nxt;
    }

    const float x2 = x * x, y2 = y * y, z2 = z * z;
    sh[0]  = 0.28209479177387814f;
    sh[1]  = 0.4886025119029199f * y;
    sh[2]  = 0.4886025119029199f * z;
    sh[3]  = 0.4886025119029199f * x;
    sh[4]  = 1.0925484305920792f * x * y;
    sh[5]  = 1.0925484305920792f * y * z;
    sh[6]  = 0.31539156525252005f * (3.0f * z2 - 1.0f);
    sh[7]  = 1.0925484305920792f * x * z;
    sh[8]  = 0.5462742152960396f * (x2 - y2);
    sh[9]  = 0.5900435899266435f * y * (3.0f * x2 - y2);
    sh[10] = 2.890611442640554f  * x * y * z;
    sh[11] = 0.4570457994644658f * y * (5.0f * z2 - 1.0f);
    sh[12] = 0.3731763325901154f * (5.0f * z2 * z - 3.0f * z);
    sh[13] = 0.4570457994644658f * x * (5.0f * z2 - 1.0f);
    sh[14] = 1.445305721320277f  * z * (x2 - y2);
    sh[15] = 0.5900435899266435f * x * (x2 - y2);
}

// ---------- single-pass scatter: edge -> per-segment slot ----------
__global__ __launch_bounds__(256) void scatter_kernel(
    const int* __restrict__ cidx, const int* __restrict__ sidx,
    int* __restrict__ cursors, int* __restrict__ ovf_cnt,
    uint2* __restrict__ ovf, unsigned int* __restrict__ eids, int cap)
{
    const int e = blockIdx.x * 256 + threadIdx.x;
    const int seg = (cidx[e] << 2) | sidx[e];
    const int pos = atomicAdd(&cursors[seg], 1);
    if (pos < cap) {
        eids[seg * cap + pos] = (unsigned)e;
    } else {
        const int o = atomicAdd(ovf_cnt, 1);
        if (o < OVF_CAP) ovf[o] = make_uint2((unsigned)seg, (unsigned)e);
    }
}

// ---------- compute: block = 8 centers (32 segments), balanced group walk ----------
__global__ __launch_bounds__(256) void compute_kernel(
    const unsigned int* __restrict__ eids, const int* __restrict__ cursors,
    const float* __restrict__ vectors,
    const float* __restrict__ rw,    // (4,12,8)
    float* __restrict__ out, int cap)
{
    __shared__ float tile[8 * 512];   // 16 KB accumulation tile (8 centers x 512)
    __shared__ int soff[33];          // prefix over the block's 32 segment counts

    const int t    = threadIdx.x;
    const int b    = blockIdx.x;      // 4096 blocks
    const int seg0 = b * 32;
    const int n    = t & 7;           // radial index owned by this lane
    const int g    = t >> 3;          // group 0..31

    // per-lane W slice: Wn[l][bb] = rw[(l*12+bb)*8 + n]
    float Wn[4][N_BASIS];
    #pragma unroll
    for (int l = 0; l < 4; ++l)
        #pragma unroll
        for (int bb = 0; bb < N_BASIS; ++bb)
            Wn[l][bb] = rw[(l * N_BASIS + bb) * 8 + n];

    // zero the tile
    #pragma unroll
    for (int i = t; i < 4096; i += 256) tile[i] = 0.0f;

    // counts + inclusive scan (lanes 0..31 of wave 0)
    if (t < 32) {
        int c = cursors[seg0 + t];
        c = (c < cap) ? c : cap;      // overflowed edges handled by fixup
        int v = c;
        #pragma unroll
        for (int d = 1; d < 32; d <<= 1) {
            int u = __shfl_up(v, d, 32);
            if (t >= d) v += u;
        }
        soff[t + 1] = v;
        if (t == 0) soff[0] = 0;
    }
    __syncthreads();

    const int T  = soff[32];
    const int lo = (T * g) >> 5;          // balanced split of the block's edges
    const int hi = (T * (g + 1)) >> 5;

    if (lo < hi) {
        int cur = 0;
        int nxt = soff[1];
        while (nxt <= lo) { ++cur; nxt = soff[cur + 1]; }
        int segstart = soff[cur];
        int eidbase  = (seg0 + cur) * cap;

        float acc[16];
        #pragma unroll
        for (int L = 0; L < 16; ++L) acc[L] = 0.0f;
        bool touched = false;

        for (int j = lo; j < hi; ++j) {
            while (j >= nxt) {
                if (touched) {
                    float* p = tile + (cur >> 2) * 512 + (cur & 3) * 8 + n;
                    #pragma unroll
                    for (int L = 0; L < 16; ++L) atomicAdd(p + L * 32, acc[L]);
                    #pragma unroll
                    for (int L = 0; L < 16; ++L) acc[L] = 0.0f;
                    touched = false;
                }
                ++cur;
                segstart = nxt;
                nxt = soff[cur + 1];
                eidbase += cap;
            }
            const unsigned eid = eids[eidbase + (j - segstart)];
            const float x = vectors[3 * eid + 0];
            const float y = vectors[3 * eid + 1];
            const float z = vectors[3 * eid + 2];

            float ph[N_BASIS], sh[16];
            compute_edge(x, y, z, ph, sh);

            float rad[4];
            #pragma unroll
            for (int l = 0; l < 4; ++l) {
                float a = 0.0f;
                #pragma unroll
                for (int bb = 0; bb < N_BASIS; ++bb)
                    a = fmaf(ph[bb], Wn[l][bb], a);
                rad[l] = a;
            }
            #pragma unroll
            for (int L = 0; L < 16; ++L) {
                const int l = (L == 0) ? 0 : (L < 4) ? 1 : (L < 9) ? 2 : 3;
                acc[L] = fmaf(sh[L], rad[l], acc[L]);
            }
            touched = true;
        }
        if (touched) {
            float* p = tile + (cur >> 2) * 512 + (cur & 3) * 8 + n;
            #pragma unroll
            for (int L = 0; L < 16; ++L) atomicAdd(p + L * 32, acc[L]);
        }
    }
    __syncthreads();

    // coalesced store of the block's 8 centers (16 KB)
    float4*       o4 = (float4*)(out + (size_t)b * 4096);
    const float4* t4 = (const float4*)tile;
    #pragma unroll
    for (int k = 0; k < 4; ++k) o4[k * 256 + t] = t4[k * 256 + t];
}

// ---------- fixup: overflow edges added atomically (normally empty) ----------
__global__ __launch_bounds__(256) void fixup_kernel(
    const int* __restrict__ ovf_cnt, const uint2* __restrict__ ovf,
    const float* __restrict__ vectors, const float* __restrict__ rw,
    float* __restrict__ out)
{
    const int m = (*ovf_cnt < OVF_CAP) ? *ovf_cnt : OVF_CAP;
    for (int i = blockIdx.x * blockDim.x + threadIdx.x; i < m;
         i += gridDim.x * blockDim.x) {
        const unsigned seg = ovf[i].x;
        const unsigned e   = ovf[i].y;
        float ph[N_BASIS], sh[16];
        compute_edge(vectors[3*e], vectors[3*e+1], vectors[3*e+2], ph, sh);
        float* op = out + (size_t)(seg >> 2) * 512 + (seg & 3) * 8;
        for (int l = 0; l < 4; ++l) {
            const int L0 = l * l;
            const int ml = 2 * l + 1;
            for (int nn = 0; nn < 8; ++nn) {
                float rad = 0.0f;
                for (int bb = 0; bb < N_BASIS; ++bb)
                    rad = fmaf(ph[bb], rw[(l * N_BASIS + bb) * 8 + nn], rad);
                for (int mm = 0; mm < ml; ++mm)
                    atomicAdd(op + (L0 + mm) * 32 + nn, sh[L0 + mm] * rad);
            }
        }
    }
}

// ---------- fallback: atomic kernel (used only if ws too small) ----------
__global__ __launch_bounds__(256) void atomic_kernel(
    const float* __restrict__ vectors, const float* __restrict__ rw,
    const int* __restrict__ cidx, const int* __restrict__ sidx,
    float* __restrict__ out)
{
    const int e = blockIdx.x * 256 + threadIdx.x;
    if (e >= N_EDGES) return;
    float ph[N_BASIS], sh[16];
    compute_edge(vectors[3*e], vectors[3*e+1], vectors[3*e+2], ph, sh);
    float* op = out + (size_t)cidx[e] * 512 + sidx[e] * 8;
    for (int l = 0; l < 4; ++l) {
        const int L0 = l * l;
        const int ml = 2 * l + 1;
        for (int nn = 0; nn < 8; ++nn) {
            float rad = 0.0f;
            for (int bb = 0; bb < N_BASIS; ++bb)
                rad = fmaf(ph[bb], rw[(l * N_BASIS + bb) * 8 + nn], rad);
            for (int mm = 0; mm < ml; ++mm)
                atomicAdd(op + (L0 + mm) * 32 + nn, sh[L0 + mm] * rad);
        }
    }
}

extern "C" void kernel_launch(void* const* d_in, const int* in_sizes, int n_in,
                              void* d_out, int out_size, void* d_ws, size_t ws_size,
                              hipStream_t stream) {
    const float* vectors = (const float*)d_in[0];
    const float* rw      = (const float*)d_in[1];
    const int*   cidx    = (const int*)d_in[2];
    const int*   sidx    = (const int*)d_in[3];
    float*       out     = (float*)d_out;

    const size_t need32 = (size_t)WS_EIDS + (size_t)N_SEG * 32 * 4;  // ~17.3 MB
    const size_t need16 = (size_t)WS_EIDS + (size_t)N_SEG * 16 * 4;  // ~9.4 MB
    const int cap = (ws_size >= need32) ? 32 : ((ws_size >= need16) ? 16 : 0);

    if (cap == 0) {
        hipMemsetAsync(out, 0, (size_t)out_size * sizeof(float), stream);
        hipLaunchKernelGGL(atomic_kernel, dim3(N_EDGES / 256), dim3(256), 0, stream,
                           vectors, rw, cidx, sidx, out);
        return;
    }

    char* ws = (char*)d_ws;
    int*          cursors = (int*)(ws + WS_CURSORS);
    int*          ovfcnt  = (int*)(ws + WS_OVFCNT);
    uint2*        ovf     = (uint2*)(ws + WS_OVF);
    unsigned int* eids    = (unsigned int*)(ws + WS_EIDS);

    // zero cursors + overflow counter in one shot
    hipMemsetAsync(ws, 0, WS_OVFCNT + 64, stream);

    hipLaunchKernelGGL(scatter_kernel, dim3(N_EDGES / 256), dim3(256), 0, stream,
                       cidx, sidx, cursors, ovfcnt, ovf, eids, cap);
    hipLaunchKernelGGL(compute_kernel, dim3(N_SEG / 32), dim3(256), 0, stream,
                       eids, cursors, vectors, rw, out, cap);
    hipLaunchKernelGGL(fixup_kernel, dim3(4), dim3(256), 0, stream,
                       ovfcnt, ovf, vectors, rw, out);
}

// Round 2
// 329.750 us; speedup vs baseline: 1.0034x; 1.0034x over previous
//
#include <hip/hip_runtime.h>
#include <math.h>

#define N_EDGES    1048576
#define N_CENTERS  32768
#define N_SEG      131072            // N_CENTERS * 4 species
#define N_BASIS    12

// ---- workspace layout ----
#define WS_CURSORS  0                        // int[N_SEG]           (512 KB)
#define WS_OVFCNT   (N_SEG * 4)              // int (+ pad to 64 B)
#define OVF_CAP     65536
#define WS_OVF      (N_SEG * 4 + 64)         // uint2[OVF_CAP]       (512 KB)
#define WS_EIDS     (N_SEG * 4 + 64 + OVF_CAP * 8)   // u32[N_SEG * CAP]

__device__ __forceinline__ void compute_edge(float x, float y, float z,
                                             float* __restrict__ ph,   // 12, scaled by NORM/r
                                             float* __restrict__ sh)   // 16
{
    const float r2    = fmaf(x, x, fmaf(y, y, z * z)) + 1e-12f;
    const float inv_r = rsqrtf(r2);
    const float r     = r2 * inv_r;
    x *= inv_r; y *= inv_r; z *= inv_r;

    const float t = 0.6283185307179586f * r;   // pi/5 * r
    float s1, c1;
    __sincosf(t, &s1, &c1);
    const float twoc = 2.0f * c1;
    const float scale = 0.17677669529663687f * inv_r;  // (1/sqrt(32)) / r
    float skm1 = 0.0f, sk = s1;
    #pragma unroll
    for (int b = 0; b < N_BASIS; ++b) {
        ph[b] = sk * scale;
        const float nxt = fmaf(twoc, sk, -skm1);
        skm1 = sk; sk = nxt;
    }

    const float x2 = x * x, y2 = y * y, z2 = z * z;
    sh[0]  = 0.28209479177387814f;
    sh[1]  = 0.4886025119029199f * y;
    sh[2]  = 0.4886025119029199f * z;
    sh[3]  = 0.4886025119029199f * x;
    sh[4]  = 1.0925484305920792f * x * y;
    sh[5]  = 1.0925484305920792f * y * z;
    sh[6]  = 0.31539156525252005f * (3.0f * z2 - 1.0f);
    sh[7]  = 1.0925484305920792f * x * z;
    sh[8]  = 0.5462742152960396f * (x2 - y2);
    sh[9]  = 0.5900435899266435f * y * (3.0f * x2 - y2);
    sh[10] = 2.890611442640554f  * x * y * z;
    sh[11] = 0.4570457994644658f * y * (5.0f * z2 - 1.0f);
    sh[12] = 0.3731763325901154f * (5.0f * z2 * z - 3.0f * z);
    sh[13] = 0.4570457994644658f * x * (5.0f * z2 - 1.0f);
    sh[14] = 1.445305721320277f  * z * (x2 - y2);
    sh[15] = 0.5900435899266435f * x * (x2 - y2);
}

// ---------- single-pass scatter: edge -> per-segment slot ----------
__global__ __launch_bounds__(256) void scatter_kernel(
    const int* __restrict__ cidx, const int* __restrict__ sidx,
    int* __restrict__ cursors, int* __restrict__ ovf_cnt,
    uint2* __restrict__ ovf, unsigned int* __restrict__ eids, int cap)
{
    const int e = blockIdx.x * 256 + threadIdx.x;
    const int seg = (cidx[e] << 2) | sidx[e];
    const int pos = atomicAdd(&cursors[seg], 1);
    if (pos < cap) {
        eids[seg * cap + pos] = (unsigned)e;
    } else {
        const int o = atomicAdd(ovf_cnt, 1);
        if (o < OVF_CAP) ovf[o] = make_uint2((unsigned)seg, (unsigned)e);
    }
}

// ---------- compute: block = 8 centers (32 segments) ----------
// Phase 1: parallel staged gather (all 256 threads issue eid+vector loads -> LDS)
// Phase 2: group walk entirely from LDS (8-lane b128 broadcast)
__global__ __launch_bounds__(256) void compute_kernel(
    const unsigned int* __restrict__ eids, const int* __restrict__ cursors,
    const float* __restrict__ vectors,
    const float* __restrict__ rw,    // (4,12,8)
    float* __restrict__ out, int cap)
{
    __shared__ float  tile[8 * 512];  // 16 KB accumulation tile
    __shared__ float4 pay[1024];      // 16 KB payload (worst case 32 segs * cap 32)
    __shared__ int    soff[33];

    const int t    = threadIdx.x;
    const int b    = blockIdx.x;      // 4096 blocks
    const int seg0 = b * 32;
    const int n    = t & 7;           // radial index owned by this lane
    const int g    = t >> 3;          // group 0..31

    // per-lane W slice
    float Wn[4][N_BASIS];
    #pragma unroll
    for (int l = 0; l < 4; ++l)
        #pragma unroll
        for (int bb = 0; bb < N_BASIS; ++bb)
            Wn[l][bb] = rw[(l * N_BASIS + bb) * 8 + n];

    // zero the tile
    #pragma unroll
    for (int i = t; i < 4096; i += 256) tile[i] = 0.0f;

    // counts + inclusive scan (lanes 0..31 of wave 0)
    if (t < 32) {
        int c = cursors[seg0 + t];
        c = (c < cap) ? c : cap;      // overflow handled by fixup
        int v = c;
        #pragma unroll
        for (int d = 1; d < 32; d <<= 1) {
            int u = __shfl_up(v, d, 32);
            if (t >= d) v += u;
        }
        soff[t + 1] = v;
        if (t == 0) soff[0] = 0;
    }
    __syncthreads();

    const int T = soff[32];

    // ---- phase 1: cooperative gather into pay[] ----
    for (int i = t; i < T; i += 256) {
        // binary search: largest s with soff[s] <= i  (5 fixed steps)
        int lo_ = 0, hi_ = 32;
        #pragma unroll
        for (int s = 0; s < 5; ++s) {
            const int mid = (lo_ + hi_) >> 1;
            if (soff[mid] <= i) lo_ = mid; else hi_ = mid;
        }
        const int sg = lo_;
        const unsigned eid = eids[(seg0 + sg) * cap + (i - soff[sg])];
        pay[i] = make_float4(vectors[3 * eid + 0], vectors[3 * eid + 1],
                             vectors[3 * eid + 2], __int_as_float(sg));
    }
    __syncthreads();

    // ---- phase 2: balanced group walk from LDS ----
    const int lo = (T * g) >> 5;
    const int hi = (T * (g + 1)) >> 5;

    if (lo < hi) {
        int cur = -1;
        float acc[16];
        #pragma unroll
        for (int L = 0; L < 16; ++L) acc[L] = 0.0f;

        for (int j = lo; j < hi; ++j) {
            const float4 v = pay[j];            // 8-lane broadcast b128
            const int sl = __float_as_int(v.w);
            if (sl != cur) {
                if (cur >= 0) {
                    float* p = tile + (cur >> 2) * 512 + (cur & 3) * 8 + n;
                    #pragma unroll
                    for (int L = 0; L < 16; ++L) atomicAdd(p + L * 32, acc[L]);
                    #pragma unroll
                    for (int L = 0; L < 16; ++L) acc[L] = 0.0f;
                }
                cur = sl;
            }
            float ph[N_BASIS], sh[16];
            compute_edge(v.x, v.y, v.z, ph, sh);

            float rad[4];
            #pragma unroll
            for (int l = 0; l < 4; ++l) {
                float a = 0.0f;
                #pragma unroll
                for (int bb = 0; bb < N_BASIS; ++bb)
                    a = fmaf(ph[bb], Wn[l][bb], a);
                rad[l] = a;
            }
            #pragma unroll
            for (int L = 0; L < 16; ++L) {
                const int l = (L == 0) ? 0 : (L < 4) ? 1 : (L < 9) ? 2 : 3;
                acc[L] = fmaf(sh[L], rad[l], acc[L]);
            }
        }
        if (cur >= 0) {
            float* p = tile + (cur >> 2) * 512 + (cur & 3) * 8 + n;
            #pragma unroll
            for (int L = 0; L < 16; ++L) atomicAdd(p + L * 32, acc[L]);
        }
    }
    __syncthreads();

    // coalesced store of the block's 8 centers (16 KB)
    float4*       o4 = (float4*)(out + (size_t)b * 4096);
    const float4* t4 = (const float4*)tile;
    #pragma unroll
    for (int k = 0; k < 4; ++k) o4[k * 256 + t] = t4[k * 256 + t];
}

// ---------- fixup: overflow edges added atomically (normally empty) ----------
__global__ __launch_bounds__(256) void fixup_kernel(
    const int* __restrict__ ovf_cnt, const uint2* __restrict__ ovf,
    const float* __restrict__ vectors, const float* __restrict__ rw,
    float* __restrict__ out)
{
    const int m = (*ovf_cnt < OVF_CAP) ? *ovf_cnt : OVF_CAP;
    for (int i = blockIdx.x * blockDim.x + threadIdx.x; i < m;
         i += gridDim.x * blockDim.x) {
        const unsigned seg = ovf[i].x;
        const unsigned e   = ovf[i].y;
        float ph[N_BASIS], sh[16];
        compute_edge(vectors[3*e], vectors[3*e+1], vectors[3*e+2], ph, sh);
        float* op = out + (size_t)(seg >> 2) * 512 + (seg & 3) * 8;
        for (int l = 0; l < 4; ++l) {
            const int L0 = l * l;
            const int ml = 2 * l + 1;
            for (int nn = 0; nn < 8; ++nn) {
                float rad = 0.0f;
                for (int bb = 0; bb < N_BASIS; ++bb)
                    rad = fmaf(ph[bb], rw[(l * N_BASIS + bb) * 8 + nn], rad);
                for (int mm = 0; mm < ml; ++mm)
                    atomicAdd(op + (L0 + mm) * 32 + nn, sh[L0 + mm] * rad);
            }
        }
    }
}

// ---------- fallback: atomic kernel (used only if ws too small) ----------
__global__ __launch_bounds__(256) void atomic_kernel(
    const float* __restrict__ vectors, const float* __restrict__ rw,
    const int* __restrict__ cidx, const int* __restrict__ sidx,
    float* __restrict__ out)
{
    const int e = blockIdx.x * 256 + threadIdx.x;
    if (e >= N_EDGES) return;
    float ph[N_BASIS], sh[16];
    compute_edge(vectors[3*e], vectors[3*e+1], vectors[3*e+2], ph, sh);
    float* op = out + (size_t)cidx[e] * 512 + sidx[e] * 8;
    for (int l = 0; l < 4; ++l) {
        const int L0 = l * l;
        const int ml = 2 * l + 1;
        for (int nn = 0; nn < 8; ++nn) {
            float rad = 0.0f;
            for (int bb = 0; bb < N_BASIS; ++bb)
                rad = fmaf(ph[bb], rw[(l * N_BASIS + bb) * 8 + nn], rad);
            for (int mm = 0; mm < ml; ++mm)
                atomicAdd(op + (L0 + mm) * 32 + nn, sh[L0 + mm] * rad);
        }
    }
}

extern "C" void kernel_launch(void* const* d_in, const int* in_sizes, int n_in,
                              void* d_out, int out_size, void* d_ws, size_t ws_size,
                              hipStream_t stream) {
    const float* vectors = (const float*)d_in[0];
    const float* rw      = (const float*)d_in[1];
    const int*   cidx    = (const int*)d_in[2];
    const int*   sidx    = (const int*)d_in[3];
    float*       out     = (float*)d_out;

    const size_t need32 = (size_t)WS_EIDS + (size_t)N_SEG * 32 * 4;  // ~17.3 MB
    const size_t need16 = (size_t)WS_EIDS + (size_t)N_SEG * 16 * 4;  // ~9.4 MB
    const int cap = (ws_size >= need32) ? 32 : ((ws_size >= need16) ? 16 : 0);

    if (cap == 0) {
        hipMemsetAsync(out, 0, (size_t)out_size * sizeof(float), stream);
        hipLaunchKernelGGL(atomic_kernel, dim3(N_EDGES / 256), dim3(256), 0, stream,
                           vectors, rw, cidx, sidx, out);
        return;
    }

    char* ws = (char*)d_ws;
    int*          cursors = (int*)(ws + WS_CURSORS);
    int*          ovfcnt  = (int*)(ws + WS_OVFCNT);
    uint2*        ovf     = (uint2*)(ws + WS_OVF);
    unsigned int* eids    = (unsigned int*)(ws + WS_EIDS);

    hipMemsetAsync(ws, 0, WS_OVFCNT + 64, stream);

    hipLaunchKernelGGL(scatter_kernel, dim3(N_EDGES / 256), dim3(256), 0, stream,
                       cidx, sidx, cursors, ovfcnt, ovf, eids, cap);
    hipLaunchKernelGGL(compute_kernel, dim3(N_SEG / 32), dim3(256), 0, stream,
                       eids, cursors, vectors, rw, out, cap);
    hipLaunchKernelGGL(fixup_kernel, dim3(4), dim3(256), 0, stream,
                       ovfcnt, ovf, vectors, rw, out);
}